// Round 1
// baseline (682.099 us; speedup 1.0000x reference)
//
#include <hip/hip_runtime.h>

#define NROWS 65536   // B*H*W
#define DDIM  256
#define KCODES 1024
#define HWSZ  1024

#define BN 64   // rows per block
#define BK 64   // codes per chunk
#define DT 32   // d-tile for E staging

// ---------------- Kernel 1: e2[k] = sum_d embed[d][k]^2 ----------------
__global__ void e2_kernel(const float* __restrict__ embed, float* __restrict__ e2) {
    int k = blockIdx.x * blockDim.x + threadIdx.x;
    if (k >= KCODES) return;
    float s = 0.f;
    for (int d = 0; d < DDIM; ++d) {
        float v = embed[d * KCODES + k];
        s += v * v;
    }
    e2[k] = s;
}

// ---------------- Kernel 2: fused GEMM + argmin ----------------
// Block: 256 threads, 64 rows. Xt staged transposed in LDS (reused over all k),
// E staged in [DT][BK] slices. 4x4 register blocking, float4 LDS reads.
__global__ __launch_bounds__(256, 2)
void argmin_kernel(const float* __restrict__ x, const float* __restrict__ embed,
                   const float* __restrict__ e2, int* __restrict__ ind) {
    __shared__ __align__(16) float Xt[DDIM][BN];   // 64 KiB, Xt[d][row]
    __shared__ __align__(16) float Es[DT][BK];     // 8 KiB

    const int t  = threadIdx.x;
    const int n0 = blockIdx.x * BN;
    const int b  = n0 / HWSZ;
    const int hw0 = n0 % HWSZ;
    const float* xb = x + (size_t)b * DDIM * HWSZ + hw0;

    const int r  = t & 63;    // 0..63
    const int dg = t >> 6;    // 0..3 (wave id)

    // Stage X tile transposed: Xt[d][row]. Coalesced 256B global loads.
    for (int it = 0; it < DDIM / 4; ++it) {
        int d = it * 4 + dg;
        Xt[d][r] = xb[d * HWSZ + r];
    }

    const int tx = t & 15;          // covers 64 cols (4 each)
    const int ty = t >> 4;          // covers 64 rows (4 each)
    const int r0 = ty * 4;
    const int k0l = tx * 4;

    float bv[4];
    int   bi[4];
#pragma unroll
    for (int i = 0; i < 4; ++i) { bv[i] = 3.4e38f; bi[i] = 0; }

    __syncthreads();

    for (int kc = 0; kc < KCODES; kc += BK) {
        float acc[4][4];
#pragma unroll
        for (int i = 0; i < 4; ++i)
#pragma unroll
            for (int j = 0; j < 4; ++j) acc[i][j] = 0.f;

        for (int dt = 0; dt < DDIM; dt += DT) {
            __syncthreads();   // protect Es from previous compute readers
            // stage Es[dd][kk]: 2048 floats, 8 iters, coalesced 256B loads
#pragma unroll
            for (int it = 0; it < 8; ++it) {
                int dd = it * 4 + dg;
                Es[dd][r] = embed[(dt + dd) * KCODES + kc + r];
            }
            __syncthreads();
#pragma unroll
            for (int dd = 0; dd < DT; ++dd) {
                const float4 xv = *(const float4*)(&Xt[dt + dd][r0]);
                const float4 ev = *(const float4*)(&Es[dd][k0l]);
                acc[0][0] += xv.x * ev.x; acc[0][1] += xv.x * ev.y;
                acc[0][2] += xv.x * ev.z; acc[0][3] += xv.x * ev.w;
                acc[1][0] += xv.y * ev.x; acc[1][1] += xv.y * ev.y;
                acc[1][2] += xv.y * ev.z; acc[1][3] += xv.y * ev.w;
                acc[2][0] += xv.z * ev.x; acc[2][1] += xv.z * ev.y;
                acc[2][2] += xv.z * ev.z; acc[2][3] += xv.z * ev.w;
                acc[3][0] += xv.w * ev.x; acc[3][1] += xv.w * ev.y;
                acc[3][2] += xv.w * ev.z; acc[3][3] += xv.w * ev.w;
            }
        }

        // dist = e2[k] - 2*dot  (|z|^2 constant per row, irrelevant for argmin)
        const float4 e2v = *(const float4*)(&e2[kc + k0l]);
        const float e2a[4] = { e2v.x, e2v.y, e2v.z, e2v.w };
#pragma unroll
        for (int i = 0; i < 4; ++i) {
            float v = e2a[0] - 2.f * acc[i][0];
            int   idx = kc + k0l;
#pragma unroll
            for (int j = 1; j < 4; ++j) {
                float vj = e2a[j] - 2.f * acc[i][j];
                if (vj < v) { v = vj; idx = kc + k0l + j; }   // strict <: lower idx wins ties
            }
            // butterfly over the 16 tx-lanes (same wave, xor masks 1,2,4,8)
#pragma unroll
            for (int m = 1; m <= 8; m <<= 1) {
                float ov = __shfl_xor(v, m, 64);
                int   oi = __shfl_xor(idx, m, 64);
                if (ov < v || (ov == v && oi < idx)) { v = ov; idx = oi; }
            }
            if (v < bv[i]) { bv[i] = v; bi[i] = idx; }        // strict <: earlier chunk wins ties
        }
    }

    if (tx == 0) {
#pragma unroll
        for (int i = 0; i < 4; ++i) ind[n0 + r0 + i] = bi[i];
    }
}

// ---------------- Kernel 3: gather + write both outputs ----------------
__global__ void gather_kernel(const float* __restrict__ embed, const int* __restrict__ ind,
                              float* __restrict__ out) {
    unsigned i = blockIdx.x * 256u + threadIdx.x;   // [B][D][HW], 2^24 total
    int hw = i & 1023;
    int d  = (i >> 10) & 255;
    int b  = i >> 18;
    int idx = ind[(b << 10) + hw];
    float v = embed[(d << 10) + idx];
    out[i] = v;
    out[i + (1u << 24)] = v;
}

extern "C" void kernel_launch(void* const* d_in, const int* in_sizes, int n_in,
                              void* d_out, int out_size, void* d_ws, size_t ws_size,
                              hipStream_t stream) {
    const float* x     = (const float*)d_in[0];
    const float* embed = (const float*)d_in[1];
    float* out = (float*)d_out;

    int*   ind = (int*)d_ws;                                 // 65536 * 4 B
    float* e2  = (float*)((char*)d_ws + (size_t)NROWS * 4);  // 1024 * 4 B

    e2_kernel<<<KCODES / 256, 256, 0, stream>>>(embed, e2);
    argmin_kernel<<<NROWS / BN, 256, 0, stream>>>(x, embed, e2, ind);
    gather_kernel<<<(1u << 24) / 256, 256, 0, stream>>>(embed, ind, out);
}

// Round 2
// 236.616 us; speedup vs baseline: 2.8827x; 2.8827x over previous
//
#include <hip/hip_runtime.h>
#include <string.h>

typedef __bf16 bf16x4 __attribute__((ext_vector_type(4)));
typedef __bf16 bf16x8 __attribute__((ext_vector_type(8)));
typedef float  f32x16 __attribute__((ext_vector_type(16)));

#define HWSZ   1024
#define DDIM   256
#define KCODES 1024
#define NROWS  65536
#define NSTEPS 68       // 4 code-chunks * 17 k-steps
#define TAU    0.05f    // dot-space gap threshold for exact-recheck

__device__ __forceinline__ unsigned short f2bf(float f) {
    unsigned u = __float_as_uint(f);
    u += 0x7FFFu + ((u >> 16) & 1u);          // RNE
    return (unsigned short)(u >> 16);
}
__device__ __forceinline__ float bf2f(unsigned short h) {
    return __uint_as_float(((unsigned)h) << 16);
}

// ---------------- e2[k] = sum_d embed[d][k]^2 ----------------
__global__ void e2_kernel(const float* __restrict__ embed, float* __restrict__ e2) {
    int k = blockIdx.x * blockDim.x + threadIdx.x;
    if (k >= KCODES) return;
    float s = 0.f;
    for (int d = 0; d < DDIM; ++d) {
        float v = embed[(size_t)d * KCODES + k];
        s = fmaf(v, v, s);
    }
    e2[k] = s;
}

// ---------------- prep: build EHAT (split embed, MFMA-A lane order) ----------------
// layout: [cc 4][ks 17][hilo 2][cf32 8][slot 64] x 16B ; A-frag: code = cf32*32+(slot&31),
// d' = ks*16 + 8*(slot>>5) + j ; d'<256 -> embed, d'==256 -> -e2/2, else 0.
__global__ void prep_e(const float* __restrict__ embed, const float* __restrict__ e2,
                       uint4* __restrict__ ehat) {
    int id = blockIdx.x * 256 + threadIdx.x;
    if (id >= NSTEPS * 16 * 64) return;   // 69632
    int slot = id & 63;
    int r = id >> 6;
    int cf32 = r & 7;  r >>= 3;
    int hilo = r & 1;  r >>= 1;
    int ks = r % 17;
    int cc = r / 17;
    int code = cc * 256 + cf32 * 32 + (slot & 31);
    int kgp  = (slot >> 5) & 1;
    unsigned short vals[8];
#pragma unroll
    for (int j = 0; j < 8; ++j) {
        int d = ks * 16 + kgp * 8 + j;
        float v;
        if (d < 256)       v = embed[(size_t)d * KCODES + code];
        else if (d == 256) v = -0.5f * e2[code];
        else               v = 0.f;
        unsigned short h = f2bf(v);
        vals[j] = (hilo == 0) ? h : f2bf(v - bf2f(h));
    }
    uint4 o;
    __builtin_memcpy(&o, vals, 16);
    ehat[id] = o;
}

// ---------------- main: 3-MFMA bf16-split GEMM + fused argmax(dot') ----------------
__global__ __launch_bounds__(512, 2)
void vq_main(const float* __restrict__ x, const uint4* __restrict__ ehat,
             int* __restrict__ ind, int* __restrict__ count, int* __restrict__ list) {
    __shared__ __align__(16) char smem[163840];
    char* XS = smem;               // 131072 B: [g 4][ks 16][hilo 2][dq 4][pix32 32][d4 4]*2B
    char* ES = smem + 131072;      // 2 x 16384 B double buffer

    const int t    = threadIdx.x;
    const int lane = t & 63;
    const int w    = t >> 6;
    const int wr   = w >> 1;       // 0..3 code quarter
    const int wc   = w & 1;        // 0..1 pixel half
    const int kg   = (lane >> 5) & 1;
    const int l31  = lane & 31;

    const int pix0 = blockIdx.x * 128;
    const int b0   = pix0 >> 10;
    const int hw0  = pix0 & 1023;
    const float* xb = x + (size_t)b0 * (DDIM * HWSZ) + hw0;

    // ---- stage X tile: convert f32 -> bf16 hi/lo into subtiled LDS ----
    {
        int pix = t & 127, dq = t >> 7;     // dq 0..3
        int g = pix >> 5, pl = pix & 31;
        for (int p = 0; p < 16; ++p) {
            int d0 = p * 16 + dq * 4;
            const float* xp = xb + (size_t)d0 * HWSZ + pix;
            float v0 = xp[0], v1 = xp[HWSZ], v2 = xp[2 * HWSZ], v3 = xp[3 * HWSZ];
            unsigned short h0 = f2bf(v0), h1 = f2bf(v1), h2 = f2bf(v2), h3 = f2bf(v3);
            unsigned short q0 = f2bf(v0 - bf2f(h0)), q1 = f2bf(v1 - bf2f(h1));
            unsigned short q2 = f2bf(v2 - bf2f(h2)), q3 = f2bf(v3 - bf2f(h3));
            ushort4 hv; hv.x = h0; hv.y = h1; hv.z = h2; hv.w = h3;
            ushort4 lv; lv.x = q0; lv.y = q1; lv.z = q2; lv.w = q3;
            char* tile = XS + (((g * 16 + p) * 2) << 10);
            *(ushort4*)(tile + dq * 256 + pl * 8) = hv;
            *(ushort4*)(tile + 1024 + dq * 256 + pl * 8) = lv;
        }
    }
    // ---- prologue: stage step 0 into ES buf0 (straight 16 KiB copy) ----
    {
        uint4 a = ehat[t * 2], b = ehat[t * 2 + 1];
        uint4* sd = (uint4*)ES;
        sd[t * 2] = a; sd[t * 2 + 1] = b;
    }
    __syncthreads();

    float bv1[2] = { -3.4e38f, -3.4e38f };
    float bv2[2] = { -3.4e38f, -3.4e38f };
    int   bi1[2] = { 0, 0 };

    int cur = 0;
    for (int cc = 0; cc < 4; ++cc) {
        f32x16 acc[2][2];
#pragma unroll
        for (int i = 0; i < 2; ++i)
#pragma unroll
            for (int j = 0; j < 2; ++j)
#pragma unroll
                for (int e = 0; e < 16; ++e) acc[i][j][e] = 0.f;

        for (int ks = 0; ks < 17; ++ks) {
            int step = cc * 17 + ks;
            bool more = (step + 1 < NSTEPS);
            uint4 r0, r1;
            if (more) {
                const uint4* gs = ehat + (size_t)(step + 1) * 1024;
                r0 = gs[t * 2]; r1 = gs[t * 2 + 1];
            }
            const char* eb = ES + (cur << 14);
            bf16x8 Ah[2], Al[2];
#pragma unroll
            for (int cf = 0; cf < 2; ++cf) {
                Ah[cf] = *(const bf16x8*)(eb + ((wr * 2 + cf) << 10) + lane * 16);
                Al[cf] = *(const bf16x8*)(eb + ((8 + wr * 2 + cf) << 10) + lane * 16);
            }
            bf16x8 Bh[2], Bl[2];
            if (ks < 16) {
#pragma unroll
                for (int pf = 0; pf < 2; ++pf) {
                    const char* tile = XS + ((((wc * 2 + pf) * 16 + ks) * 2) << 10);
                    const char* p0 = tile + (2 * kg) * 256 + l31 * 8;
                    bf16x4 a0 = *(const bf16x4*)p0;
                    bf16x4 a1 = *(const bf16x4*)(p0 + 256);
                    Bh[pf] = __builtin_shufflevector(a0, a1, 0, 1, 2, 3, 4, 5, 6, 7);
                    bf16x4 c0 = *(const bf16x4*)(p0 + 1024);
                    bf16x4 c1 = *(const bf16x4*)(p0 + 1024 + 256);
                    Bl[pf] = __builtin_shufflevector(c0, c1, 0, 1, 2, 3, 4, 5, 6, 7);
                }
            } else {
                unsigned short carr[8] = { (unsigned short)(kg == 0 ? 0x3F80 : 0), 0,0,0,0,0,0,0 };
                bf16x8 cb; __builtin_memcpy(&cb, carr, 16);
                Bh[0] = cb; Bh[1] = cb; Bl[0] = cb; Bl[1] = cb;
            }
#pragma unroll
            for (int cf = 0; cf < 2; ++cf)
#pragma unroll
                for (int pf = 0; pf < 2; ++pf) {
                    acc[cf][pf] = __builtin_amdgcn_mfma_f32_32x32x16_bf16(Ah[cf], Bh[pf], acc[cf][pf], 0, 0, 0);
                    acc[cf][pf] = __builtin_amdgcn_mfma_f32_32x32x16_bf16(Al[cf], Bh[pf], acc[cf][pf], 0, 0, 0);
                    if (ks < 16)
                        acc[cf][pf] = __builtin_amdgcn_mfma_f32_32x32x16_bf16(Ah[cf], Bl[pf], acc[cf][pf], 0, 0, 0);
                }
            if (more) {
                uint4* sd = (uint4*)(ES + ((cur ^ 1) << 14));
                sd[t * 2] = r0; sd[t * 2 + 1] = r1;
            }
            __syncthreads();
            cur ^= 1;
        }
        // ---- per-cc argmax reduce (maximize dot' = x.e - e2/2) ----
#pragma unroll
        for (int pf = 0; pf < 2; ++pf) {
            float v1 = -3.4e38f, v2 = -3.4e38f; int i1 = 0;
#pragma unroll
            for (int cf = 0; cf < 2; ++cf)
#pragma unroll
                for (int r = 0; r < 16; ++r) {
                    float v = acc[cf][pf][r];
                    int code = cc * 256 + (wr * 2 + cf) * 32 + (r & 3) + 8 * (r >> 2) + 4 * kg;
                    if (v > v1) { v2 = v1; v1 = v; i1 = code; }
                    else if (v > v2) v2 = v;
                }
            float ov1 = __shfl_xor(v1, 32, 64);
            int   oi1 = __shfl_xor(i1, 32, 64);
            float ov2 = __shfl_xor(v2, 32, 64);
            float nv2 = fmaxf(fmaxf(v2, ov2), fminf(v1, ov1));
            if (ov1 > v1 || (ov1 == v1 && oi1 < i1)) { v1 = ov1; i1 = oi1; }
            v2 = nv2;
            float m2 = fmaxf(fmaxf(bv2[pf], v2), fminf(bv1[pf], v1));
            if (v1 > bv1[pf] || (v1 == bv1[pf] && i1 < bi1[pf])) { bv1[pf] = v1; bi1[pf] = i1; }
            bv2[pf] = m2;
        }
    }

    // ---- cross-wave merge via scratch in ES region ----
    float* sv = (float*)ES;            // [128][4]
    float* sw = (float*)(ES + 2048);
    int*   si = (int*)(ES + 4096);
    if (lane < 32) {
#pragma unroll
        for (int pf = 0; pf < 2; ++pf) {
            int pix = wc * 64 + pf * 32 + lane;
            sv[pix * 4 + wr] = bv1[pf];
            sw[pix * 4 + wr] = bv2[pf];
            si[pix * 4 + wr] = bi1[pf];
        }
    }
    __syncthreads();
    if (t < 128) {
        int pix = t;
        float V1 = -3.4e38f, V2 = -3.4e38f; int I1 = 0;
#pragma unroll
        for (int q = 0; q < 4; ++q) {
            float a1 = sv[pix * 4 + q], a2 = sw[pix * 4 + q]; int ai = si[pix * 4 + q];
            float m2 = fmaxf(fmaxf(V2, a2), fminf(V1, a1));
            if (a1 > V1 || (a1 == V1 && ai < I1)) { V1 = a1; I1 = ai; }
            V2 = m2;
        }
        ind[pix0 + pix] = I1;
        if (V1 - V2 < TAU) {
            int pos = atomicAdd(count, 1);
            list[pos] = pix0 + pix;
        }
    }
}

// ---------------- fixup: exact f32 re-argmin for flagged pixels ----------------
__global__ void fixup_kernel(const float* __restrict__ x, const float* __restrict__ embed,
                             const float* __restrict__ e2, int* __restrict__ ind,
                             const int* __restrict__ count, const int* __restrict__ list) {
    __shared__ float swv[4];
    __shared__ int   swi[4];
    int nf = *count;
    for (int ii = blockIdx.x; ii < nf; ii += gridDim.x) {
        int pix = list[ii];
        int b = pix >> 10, hw = pix & 1023;
        const float* xr = x + (size_t)b * (DDIM * HWSZ) + hw;
        int c0 = threadIdx.x;
        float d0 = 0, d1 = 0, d2 = 0, d3 = 0, sx = 0;
        for (int d = 0; d < DDIM; ++d) {
            float xv = xr[(size_t)d * HWSZ];
            const float* er = embed + (size_t)d * KCODES + c0;
            sx = fmaf(xv, xv, sx);
            d0 = fmaf(xv, er[0],   d0);
            d1 = fmaf(xv, er[256], d1);
            d2 = fmaf(xv, er[512], d2);
            d3 = fmaf(xv, er[768], d3);
        }
        float bv = sx - 2.f * d0 + e2[c0]; int bi = c0;
        float w1 = sx - 2.f * d1 + e2[c0 + 256]; if (w1 < bv) { bv = w1; bi = c0 + 256; }
        float w2 = sx - 2.f * d2 + e2[c0 + 512]; if (w2 < bv) { bv = w2; bi = c0 + 512; }
        float w3 = sx - 2.f * d3 + e2[c0 + 768]; if (w3 < bv) { bv = w3; bi = c0 + 768; }
        for (int m = 1; m <= 32; m <<= 1) {
            float ov = __shfl_xor(bv, m, 64);
            int   oi = __shfl_xor(bi, m, 64);
            if (ov < bv || (ov == bv && oi < bi)) { bv = ov; bi = oi; }
        }
        if ((threadIdx.x & 63) == 0) { swv[threadIdx.x >> 6] = bv; swi[threadIdx.x >> 6] = bi; }
        __syncthreads();
        if (threadIdx.x == 0) {
            float V = swv[0]; int I = swi[0];
            for (int q = 1; q < 4; ++q)
                if (swv[q] < V || (swv[q] == V && swi[q] < I)) { V = swv[q]; I = swi[q]; }
            ind[pix] = I;
        }
        __syncthreads();
    }
}

// ---------------- gather: write both outputs ----------------
__global__ void gather_kernel(const float* __restrict__ embed, const int* __restrict__ ind,
                              float* __restrict__ out) {
    unsigned i = blockIdx.x * 256u + threadIdx.x;   // [B][D][HW]
    int hw = i & 1023;
    int d  = (i >> 10) & 255;
    int b  = i >> 18;
    int idx = ind[(b << 10) + hw];
    float v = embed[(d << 10) + idx];
    out[i] = v;
    out[i + (1u << 24)] = v;
}

extern "C" void kernel_launch(void* const* d_in, const int* in_sizes, int n_in,
                              void* d_out, int out_size, void* d_ws, size_t ws_size,
                              hipStream_t stream) {
    const float* x     = (const float*)d_in[0];
    const float* embed = (const float*)d_in[1];
    float* out = (float*)d_out;
    char* ws = (char*)d_ws;

    int*   ind   = (int*)ws;                                    // 262144 B
    float* e2    = (float*)(ws + 262144);                       // 4096 B
    uint4* ehat  = (uint4*)(ws + 266240);                       // 1114112 B
    int*   count = (int*)(ws + 266240 + 1114112);               // 4 B
    int*   list  = (int*)(ws + 266240 + 1114112 + 4);           // up to 256 KiB

    hipMemsetAsync(count, 0, 4, stream);
    e2_kernel<<<KCODES / 256, 256, 0, stream>>>(embed, e2);
    prep_e<<<(NSTEPS * 16 * 64 + 255) / 256, 256, 0, stream>>>(embed, e2, ehat);
    vq_main<<<NROWS / 128, 512, 0, stream>>>(x, ehat, ind, count, list);
    fixup_kernel<<<512, 256, 0, stream>>>(x, embed, e2, ind, count, list);
    gather_kernel<<<(1u << 24) / 256, 256, 0, stream>>>(embed, ind, out);
}

// Round 3
// 227.958 us; speedup vs baseline: 2.9922x; 1.0380x over previous
//
#include <hip/hip_runtime.h>
#include <string.h>

typedef __bf16 bf16x8 __attribute__((ext_vector_type(8)));
typedef float  f32x16 __attribute__((ext_vector_type(16)));

#define HWSZ   1024
#define DDIM   256
#define KCODES 1024
#define NROWS  65536
#define NSTEPS 64       // 4 code-chunks * 16 k-steps (e2 folded into acc init)
#define TAU    0.05f    // dot-space gap threshold for exact-recheck

__device__ __forceinline__ unsigned short f2bf(float f) {
    unsigned u = __float_as_uint(f);
    u += 0x7FFFu + ((u >> 16) & 1u);          // RNE
    return (unsigned short)(u >> 16);
}
__device__ __forceinline__ float bf2f(unsigned short h) {
    return __uint_as_float(((unsigned)h) << 16);
}

__device__ __forceinline__ void gl2lds16(const void* g, void* l) {
    __builtin_amdgcn_global_load_lds(
        (const __attribute__((address_space(1))) unsigned int*)(g),
        (__attribute__((address_space(3))) unsigned int*)(l), 16, 0, 0);
}

// ---------------- e2[k] = sum_d embed[d][k]^2 ----------------
__global__ void e2_kernel(const float* __restrict__ embed, float* __restrict__ e2) {
    int k = blockIdx.x * blockDim.x + threadIdx.x;
    if (k >= KCODES) return;
    float s = 0.f;
    for (int d = 0; d < DDIM; ++d) {
        float v = embed[(size_t)d * KCODES + k];
        s = fmaf(v, v, s);
    }
    e2[k] = s;
}

// ---------------- prep: split embed into EHAT (MFMA-A lane order) ----------------
// ehat[((step*2+hilo)*8+cf)*64+slot] (uint4 = 8 bf16): code = cf*32+(slot&31),
// d = (step&15)*16 + (slot>>5)*8 + j, code-chunk cc = step>>4.
__global__ void prep_e(const float* __restrict__ embed, uint4* __restrict__ ehat) {
    int id = blockIdx.x * 256 + threadIdx.x;
    if (id >= NSTEPS * 16 * 64) return;   // 65536
    int slot = id & 63;
    int r = id >> 6;
    int cf = r & 7;   r >>= 3;
    int hilo = r & 1; r >>= 1;
    int step = r;                  // 0..63
    int cc = step >> 4, ks = step & 15;
    int code = cc * 256 + cf * 32 + (slot & 31);
    int kgp  = slot >> 5;
    unsigned short vals[8];
#pragma unroll
    for (int j = 0; j < 8; ++j) {
        int d = ks * 16 + kgp * 8 + j;
        float v = embed[(size_t)d * KCODES + code];
        unsigned short h = f2bf(v);
        vals[j] = (hilo == 0) ? h : f2bf(v - bf2f(h));
    }
    uint4 o;
    __builtin_memcpy(&o, vals, 16);
    ehat[id] = o;
}

// ---------------- main: 3-MFMA bf16-split GEMM + fused argmax ----------------
__global__ __launch_bounds__(512, 2)
void vq_main(const float* __restrict__ x, const uint4* __restrict__ ehat,
             const float* __restrict__ e2,
             int* __restrict__ ind, int* __restrict__ count, int* __restrict__ list) {
    __shared__ __align__(16) char smem[163840];
    char* XS = smem;               // 131072 B: [g4][ks16][hilo2][kg2][pl32] x 16B
    char* ES = smem + 131072;      // 2 x 16384 B double buffer: [hilo2][cf8][slot64] x 16B

    const int t    = threadIdx.x;
    const int lane = t & 63;
    const int w    = t >> 6;
    const int wr   = w >> 1;       // 0..3 code quarter (within cc-chunk)
    const int wc   = w & 1;        // 0..1 pixel half
    const int kg   = lane >> 5;
    const int l31  = lane & 31;

    const int pix0 = blockIdx.x * 128;
    const int b0   = pix0 >> 10;
    const int hw0  = pix0 & 1023;
    const float* xb = x + (size_t)b0 * (DDIM * HWSZ) + hw0;

    // ---- prologue: DMA step 0 into ES buf0 ----
    {
        const char* gs = (const char*)ehat;
        gl2lds16(gs + w * 2048 + lane * 16, ES + w * 2048);
        gl2lds16(gs + w * 2048 + 1024 + lane * 16, ES + w * 2048 + 1024);
    }

    // ---- stage X tile: f32 -> bf16 hi/lo, b128-readable B-frag layout ----
    {
        int pix = t & 127, dq = t >> 7;        // dq 0..3
        int g = pix >> 5, pl = pix & 31;
        const float* xpix = xb + pix;
        char* gbase = XS + ((g * 16) << 11) + pl * 16;   // (((g*16+ks)*2+hilo)*2+kg)*512
        for (int pp = 0; pp < 8; ++pp) {
            int p = pp * 4 + dq;               // d8-block 0..31 ; ks=p>>1, kg=p&1
            int d0 = p * 8;
            float v[8];
#pragma unroll
            for (int j = 0; j < 8; ++j) v[j] = xpix[(size_t)(d0 + j) * HWSZ];
            unsigned short h[8], q[8];
#pragma unroll
            for (int j = 0; j < 8; ++j) {
                h[j] = f2bf(v[j]);
                q[j] = f2bf(v[j] - bf2f(h[j]));
            }
            uint4 hv, lv;
            __builtin_memcpy(&hv, h, 16);
            __builtin_memcpy(&lv, q, 16);
            char* base = gbase + ((p >> 1) << 11) + ((p & 1) << 9);
            *(uint4*)base = hv;                 // hilo=0
            *(uint4*)(base + 1024) = lv;        // hilo=1 (stride 2*512)
        }
    }
    __syncthreads();

    float bv1[2] = { -3.4e38f, -3.4e38f };
    float bv2[2] = { -3.4e38f, -3.4e38f };
    int   bi1[2] = { 0, 0 };

    int cur = 0;
    for (int cc = 0; cc < 4; ++cc) {
        f32x16 acc[2][2];
        // init acc with -e2/2 (exact f32, replaces the old 17th K-step)
#pragma unroll
        for (int r = 0; r < 16; ++r) {
            int code0 = cc * 256 + (wr * 2) * 32 + (r & 3) + 8 * (r >> 2) + 4 * kg;
            float iA = -0.5f * e2[code0];
            float iB = -0.5f * e2[code0 + 32];
            acc[0][0][r] = iA; acc[0][1][r] = iA;
            acc[1][0][r] = iB; acc[1][1][r] = iB;
        }

        for (int ks = 0; ks < 16; ++ks) {
            int step = cc * 16 + ks;
            if (step + 1 < NSTEPS) {   // DMA next step into the other buffer
                const char* gs = (const char*)ehat + ((size_t)(step + 1) << 14);
                char* ld = ES + ((cur ^ 1) << 14);
                gl2lds16(gs + w * 2048 + lane * 16, ld + w * 2048);
                gl2lds16(gs + w * 2048 + 1024 + lane * 16, ld + w * 2048 + 1024);
            }
            const char* eb = ES + (cur << 14);
            bf16x8 Ah[2], Al[2];
#pragma unroll
            for (int cf = 0; cf < 2; ++cf) {
                Ah[cf] = *(const bf16x8*)(eb + ((wr * 2 + cf) << 10) + lane * 16);
                Al[cf] = *(const bf16x8*)(eb + 8192 + ((wr * 2 + cf) << 10) + lane * 16);
            }
            bf16x8 Bh[2], Bl[2];
#pragma unroll
            for (int pf = 0; pf < 2; ++pf) {
                const char* p0 = XS + ((((wc * 2 + pf) * 16 + ks) * 2) << 10)
                               + (kg << 9) + l31 * 16;
                Bh[pf] = *(const bf16x8*)p0;
                Bl[pf] = *(const bf16x8*)(p0 + 1024);
            }
#pragma unroll
            for (int cf = 0; cf < 2; ++cf)
#pragma unroll
                for (int pf = 0; pf < 2; ++pf) {
                    acc[cf][pf] = __builtin_amdgcn_mfma_f32_32x32x16_bf16(Ah[cf], Bh[pf], acc[cf][pf], 0, 0, 0);
                    acc[cf][pf] = __builtin_amdgcn_mfma_f32_32x32x16_bf16(Al[cf], Bh[pf], acc[cf][pf], 0, 0, 0);
                    acc[cf][pf] = __builtin_amdgcn_mfma_f32_32x32x16_bf16(Ah[cf], Bl[pf], acc[cf][pf], 0, 0, 0);
                }
            __syncthreads();
            cur ^= 1;
        }

        // ---- per-cc argmax reduce (maximize dot' = x.e - e2/2) ----
#pragma unroll
        for (int pf = 0; pf < 2; ++pf) {
            float v1 = -3.4e38f, v2 = -3.4e38f; int i1 = 0;
#pragma unroll
            for (int cf = 0; cf < 2; ++cf)
#pragma unroll
                for (int r = 0; r < 16; ++r) {
                    float v = acc[cf][pf][r];
                    int code = cc * 256 + (wr * 2 + cf) * 32 + (r & 3) + 8 * (r >> 2) + 4 * kg;
                    if (v > v1) { v2 = v1; v1 = v; i1 = code; }
                    else if (v > v2) v2 = v;
                }
            float ov1 = __shfl_xor(v1, 32, 64);
            int   oi1 = __shfl_xor(i1, 32, 64);
            float ov2 = __shfl_xor(v2, 32, 64);
            float nv2 = fmaxf(fmaxf(v2, ov2), fminf(v1, ov1));
            if (ov1 > v1 || (ov1 == v1 && oi1 < i1)) { v1 = ov1; i1 = oi1; }
            v2 = nv2;
            float m2 = fmaxf(fmaxf(bv2[pf], v2), fminf(bv1[pf], v1));
            if (v1 > bv1[pf] || (v1 == bv1[pf] && i1 < bi1[pf])) { bv1[pf] = v1; bi1[pf] = i1; }
            bv2[pf] = m2;
        }
    }

    // ---- cross-wave merge via scratch (ES region is idle now) ----
    float* sv = (float*)ES;            // [128][4]
    float* sw = (float*)(ES + 2048);
    int*   si = (int*)(ES + 4096);
    if (lane < 32) {
#pragma unroll
        for (int pf = 0; pf < 2; ++pf) {
            int pix = wc * 64 + pf * 32 + lane;
            sv[pix * 4 + wr] = bv1[pf];
            sw[pix * 4 + wr] = bv2[pf];
            si[pix * 4 + wr] = bi1[pf];
        }
    }
    __syncthreads();
    if (t < 128) {
        int pix = t;
        float V1 = -3.4e38f, V2 = -3.4e38f; int I1 = 0;
#pragma unroll
        for (int q = 0; q < 4; ++q) {
            float a1 = sv[pix * 4 + q], a2 = sw[pix * 4 + q]; int ai = si[pix * 4 + q];
            float m2 = fmaxf(fmaxf(V2, a2), fminf(V1, a1));
            if (a1 > V1 || (a1 == V1 && ai < I1)) { V1 = a1; I1 = ai; }
            V2 = m2;
        }
        ind[pix0 + pix] = I1;
        if (V1 - V2 < TAU) {
            int pos = atomicAdd(count, 1);
            list[pos] = pix0 + pix;
        }
    }
}

// ---------------- fixup: exact f32 re-argmin for flagged pixels ----------------
__global__ void fixup_kernel(const float* __restrict__ x, const float* __restrict__ embed,
                             const float* __restrict__ e2, int* __restrict__ ind,
                             const int* __restrict__ count, const int* __restrict__ list) {
    __shared__ float swv[4];
    __shared__ int   swi[4];
    int nf = *count;
    for (int ii = blockIdx.x; ii < nf; ii += gridDim.x) {
        int pix = list[ii];
        int b = pix >> 10, hw = pix & 1023;
        const float* xr = x + (size_t)b * (DDIM * HWSZ) + hw;
        int c0 = threadIdx.x;
        float d0 = 0, d1 = 0, d2 = 0, d3 = 0, sx = 0;
        for (int d = 0; d < DDIM; ++d) {
            float xv = xr[(size_t)d * HWSZ];
            const float* er = embed + (size_t)d * KCODES + c0;
            sx = fmaf(xv, xv, sx);
            d0 = fmaf(xv, er[0],   d0);
            d1 = fmaf(xv, er[256], d1);
            d2 = fmaf(xv, er[512], d2);
            d3 = fmaf(xv, er[768], d3);
        }
        float bv = sx - 2.f * d0 + e2[c0]; int bi = c0;
        float w1 = sx - 2.f * d1 + e2[c0 + 256]; if (w1 < bv) { bv = w1; bi = c0 + 256; }
        float w2 = sx - 2.f * d2 + e2[c0 + 512]; if (w2 < bv) { bv = w2; bi = c0 + 512; }
        float w3 = sx - 2.f * d3 + e2[c0 + 768]; if (w3 < bv) { bv = w3; bi = c0 + 768; }
        for (int m = 1; m <= 32; m <<= 1) {
            float ov = __shfl_xor(bv, m, 64);
            int   oi = __shfl_xor(bi, m, 64);
            if (ov < bv || (ov == bv && oi < bi)) { bv = ov; bi = oi; }
        }
        if ((threadIdx.x & 63) == 0) { swv[threadIdx.x >> 6] = bv; swi[threadIdx.x >> 6] = bi; }
        __syncthreads();
        if (threadIdx.x == 0) {
            float V = swv[0]; int I = swi[0];
            for (int q = 1; q < 4; ++q)
                if (swv[q] < V || (swv[q] == V && swi[q] < I)) { V = swv[q]; I = swi[q]; }
            ind[pix] = I;
        }
        __syncthreads();
    }
}

// ---------------- gather: write both outputs, float4 ----------------
__global__ void gather_kernel(const float* __restrict__ embed, const int* __restrict__ ind,
                              float* __restrict__ out) {
    unsigned tid = blockIdx.x * 256u + threadIdx.x;   // 2^22 threads, 4 hw each
    unsigned hw4 = (tid & 255u) * 4u;
    unsigned bd  = tid >> 8;            // b*256 + d
    unsigned d   = bd & 255u, b = bd >> 8;
    const int4 idx = *(const int4*)&ind[(b << 10) + hw4];
    const float* er = embed + ((size_t)d << 10);
    float4 v;
    v.x = er[idx.x]; v.y = er[idx.y]; v.z = er[idx.z]; v.w = er[idx.w];
    size_t o = ((size_t)bd << 10) + hw4;
    *(float4*)&out[o] = v;
    *(float4*)&out[o + (1u << 24)] = v;
}

extern "C" void kernel_launch(void* const* d_in, const int* in_sizes, int n_in,
                              void* d_out, int out_size, void* d_ws, size_t ws_size,
                              hipStream_t stream) {
    const float* x     = (const float*)d_in[0];
    const float* embed = (const float*)d_in[1];
    float* out = (float*)d_out;
    char* ws = (char*)d_ws;

    int*   ind   = (int*)ws;                              // 262144 B
    float* e2    = (float*)(ws + 262144);                 // 4096 B
    uint4* ehat  = (uint4*)(ws + 266240);                 // 1048576 B
    int*   count = (int*)(ws + 266240 + 1048576);         // 4 B
    int*   list  = (int*)(ws + 266240 + 1048576 + 4);     // up to 256 KiB

    hipMemsetAsync(count, 0, 4, stream);
    e2_kernel<<<KCODES / 256, 256, 0, stream>>>(embed, e2);
    prep_e<<<(NSTEPS * 16 * 64) / 256, 256, 0, stream>>>(embed, ehat);
    vq_main<<<NROWS / 128, 512, 0, stream>>>(x, ehat, e2, ind, count, list);
    fixup_kernel<<<512, 256, 0, stream>>>(x, embed, e2, ind, count, list);
    gather_kernel<<<(1u << 22) / 256, 256, 0, stream>>>(embed, ind, out);
}